// Round 2
// baseline (94.532 us; speedup 1.0000x reference)
//
#include <hip/hip_runtime.h>
#include <math.h>

#define RES   512
#define STEPS 128
#define TILE  64
#define CHUNK 32

// One block rasterizes a 64x64 pixel tile of one (batch,stroke) image.
// raster[p,q] = sum_t exp(-(y_t-g_p)^2*inv) * exp(-(x_t-g_q)^2*inv)
// Only t's whose curve point lands within `margin` of the tile contribute
// (margin = sqrt(23/inv) -> dropped terms < 1e-10 each, <=1.3e-8 total abs).
__global__ __launch_bounds__(256) void bezier_raster_kernel(
    const float* __restrict__ cp,        // [n_img][4][2]
    const float* __restrict__ sigma_ptr, // [1]
    float* __restrict__ out)             // [n_img][512][512]
{
    __shared__ float xs[STEPS];
    __shared__ float ys[STEPS];
    __shared__ int   tlist[STEPS];
    __shared__ int   nact_s;
    __shared__ float axs[CHUNK][TILE];   // compacted Ax rows for this tile
    __shared__ float ays[CHUNK][TILE];   // compacted Ay rows for this tile

    const int img = blockIdx.z;
    const int q0  = blockIdx.x * TILE;   // x / column range
    const int p0  = blockIdx.y * TILE;   // y / row range
    const int tid = threadIdx.x;

    const float sigma  = sigma_ptr[0];
    const float inv    = 1.0f / (2.0f * sigma * sigma);
    const float margin = sqrtf(23.0f / inv);

    if (tid == 0) nact_s = 0;
    __syncthreads();

    // --- curve points + per-tile t culling (128 threads) ---
    if (tid < STEPS) {
        const float w  = (float)tid * (1.0f / (float)(STEPS - 1));
        const float v  = 1.0f - w;
        // feat[k,t] = C(3,k) * t^(3-k) * (1-t)^k, k=0..3
        const float b0 = w * w * w;
        const float b1 = 3.0f * w * w * v;
        const float b2 = 3.0f * w * v * v;
        const float b3 = v * v * v;
        const float* c = cp + (size_t)img * 8;   // [4][2]
        const float x = c[0]*b0 + c[2]*b1 + c[4]*b2 + c[6]*b3;
        const float y = c[1]*b0 + c[3]*b1 + c[5]*b2 + c[7]*b3;
        xs[tid] = x;
        ys[tid] = y;
        const float gqlo = (float)q0 * (1.0f / RES) - margin;
        const float gqhi = (float)(q0 + TILE - 1) * (1.0f / RES) + margin;
        const float gplo = (float)p0 * (1.0f / RES) - margin;
        const float gphi = (float)(p0 + TILE - 1) * (1.0f / RES) + margin;
        if (x >= gqlo && x <= gqhi && y >= gplo && y <= gphi) {
            int slot = atomicAdd(&nact_s, 1);
            tlist[slot] = tid;
        }
    }
    __syncthreads();
    const int nact = nact_s;

    float acc[4][4];
    #pragma unroll
    for (int i = 0; i < 4; ++i)
        #pragma unroll
        for (int j = 0; j < 4; ++j) acc[i][j] = 0.0f;

    const int ty = tid >> 4;   // 0..15, owns rows    p0 + ty*4 .. +3
    const int tx = tid & 15;   // 0..15, owns columns q0 + tx*4 .. +3

    for (int base = 0; base < nact; base += CHUNK) {
        const int cnt  = min(CHUNK, nact - base);
        const int cntp = (cnt + 3) & ~3;          // pad rows to unroll-4
        // --- fill compacted Ax/Ay rows (2 exps / thread-iter) ---
        for (int e = tid; e < cntp * TILE; e += 256) {
            const int r   = e >> 6;
            const int col = e & (TILE - 1);
            if (r < cnt) {
                const int   t  = tlist[base + r];
                const float gq = (float)(q0 + col) * (1.0f / RES);
                const float gp = (float)(p0 + col) * (1.0f / RES);
                const float dx = xs[t] - gq;
                const float dy = ys[t] - gp;
                axs[r][col] = __expf(-(dx * dx) * inv);
                ays[r][col] = __expf(-(dy * dy) * inv);
            } else {
                axs[r][col] = 0.0f;   // zero pad rows contribute nothing
                ays[r][col] = 0.0f;
            }
        }
        __syncthreads();
        // --- rank-1 updates: acc[i][j] += ay[p_i]*ax[q_j] ---
        for (int r = 0; r < cntp; r += 4) {
            #pragma unroll
            for (int rr = 0; rr < 4; ++rr) {
                const float4 av = *(const float4*)&ays[r + rr][ty * 4];
                const float4 bv = *(const float4*)&axs[r + rr][tx * 4];
                acc[0][0] += av.x * bv.x; acc[0][1] += av.x * bv.y;
                acc[0][2] += av.x * bv.z; acc[0][3] += av.x * bv.w;
                acc[1][0] += av.y * bv.x; acc[1][1] += av.y * bv.y;
                acc[1][2] += av.y * bv.z; acc[1][3] += av.y * bv.w;
                acc[2][0] += av.z * bv.x; acc[2][1] += av.z * bv.y;
                acc[2][2] += av.z * bv.z; acc[2][3] += av.z * bv.w;
                acc[3][0] += av.w * bv.x; acc[3][1] += av.w * bv.y;
                acc[3][2] += av.w * bv.z; acc[3][3] += av.w * bv.w;
            }
        }
        __syncthreads();
    }

    // --- stores: 4 x float4 per thread, 16B aligned, 256B runs per 16 lanes ---
    #pragma unroll
    for (int i = 0; i < 4; ++i) {
        const int p = p0 + ty * 4 + i;
        float4 v;
        v.x = acc[i][0]; v.y = acc[i][1]; v.z = acc[i][2]; v.w = acc[i][3];
        *(float4*)&out[((size_t)img * RES + p) * RES + q0 + tx * 4] = v;
    }
}

extern "C" void kernel_launch(void* const* d_in, const int* in_sizes, int n_in,
                              void* d_out, int out_size, void* d_ws, size_t ws_size,
                              hipStream_t stream) {
    const float* cp    = (const float*)d_in[0];
    const float* sigma = (const float*)d_in[1];
    float* out         = (float*)d_out;
    const int n_img    = in_sizes[0] / 8;   // batch * n_strks (16*4 = 64)
    dim3 grid(RES / TILE, RES / TILE, n_img);
    bezier_raster_kernel<<<grid, 256, 0, stream>>>(cp, sigma, out);
}